// Round 5
// baseline (764.787 us; speedup 1.0000x reference)
//
#include <hip/hip_runtime.h>
#include <cstdint>
#include <cstddef>

#define D 2048
#define L 8
#define KT 4096            // stacked K (pos|neg)
#define BM 256
#define BN 128
#define BK 32
#define NT (KT / BK)       // 128 K-tiles
#define BUFSZ ((BM + BN) * BK)   // 12288 f16 = 24 KiB per LDS buffer

typedef _Float16 f16;
typedef _Float16 f16x4 __attribute__((ext_vector_type(4)));
typedef _Float16 f16x8 __attribute__((ext_vector_type(8)));
typedef float f32x4 __attribute__((ext_vector_type(4)));

__device__ __forceinline__ void gload16(const void* g, void* l) {
  __builtin_amdgcn_global_load_lds(
      (const __attribute__((address_space(1))) void*)g,
      (__attribute__((address_space(3))) void*)l, 16, 0, 0);
}

// ---- init: A -> Abig = [[A+|A-];[A-|A+]], bias init + step-0 contribution --
__global__ __launch_bounds__(256) void k_init(
    const float* __restrict__ A, const float* __restrict__ b,
    const float* __restrict__ db1, const float* __restrict__ db2,  // layer 7
    f16* __restrict__ Ab, float* __restrict__ blbu, float* __restrict__ outacc) {
  const int m = blockIdx.x, tid = threadIdx.x;
  if (m < 2) {
    f32x4 z = {0.f, 0.f, 0.f, 0.f};
    *(f32x4*)(outacc + m * 2048 + tid * 8) = z;
    *(f32x4*)(outacc + m * 2048 + tid * 8 + 4) = z;
  }
  const int k = tid * 8;
  size_t i = (size_t)m * D + k;
  f32x4 a0 = *(const f32x4*)(A + i);
  f32x4 a1 = *(const f32x4*)(A + i + 4);
  f16x8 p, n;
  float cL = 0.f, cU = 0.f;
#pragma unroll
  for (int j = 0; j < 8; ++j) {
    float v = (j < 4) ? a0[j] : a1[j - 4];
    float pf = fmaxf(v, 0.f), nf = fminf(v, 0.f);
    p[j] = (f16)pf; n[j] = (f16)nf;
    float w1 = db1[k + j], w2 = db2[k + j];
    cL += pf * w1 + nf * w2;
    cU += pf * w2 + nf * w1;
  }
  size_t lo = (size_t)m * KT + k;
  size_t hi = (size_t)(D + m) * KT + k;
  *(f16x8*)(Ab + lo) = p;      *(f16x8*)(Ab + lo + D) = n;
  *(f16x8*)(Ab + hi) = n;      *(f16x8*)(Ab + hi + D) = p;

  __shared__ float redL[4], redU[4];
#pragma unroll
  for (int off = 32; off > 0; off >>= 1) {
    cL += __shfl_down(cL, off);
    cU += __shfl_down(cU, off);
  }
  const int wave = tid >> 6, lane = tid & 63;
  if (lane == 0) { redL[wave] = cL; redU[wave] = cU; }
  __syncthreads();
  if (tid == 0) {
    float bL = b[m] + redL[0] + redL[1] + redL[2] + redL[3];
    float bU = b[m] + redU[0] + redU[1] + redU[2] + redU[3];
    blbu[m] = bL; blbu[D + m] = bU;
  }
}

// ---- LDS-free transpose panel: Bb[n][koff+k] = (f16)src[k][n] --------------
// blk in [0,2048): 1024 blocks per matrix; block covers 64 cols x 64 k
__device__ __forceinline__ void transpose_panel(
    const float* __restrict__ srcAl, const float* __restrict__ srcAu,
    f16* __restrict__ Bb, int blk, int tid) {
  const int z = blk >> 10;
  const int rem = blk & 1023;
  const float* src = z ? srcAu : srcAl;
  const int koff = z ? D : 0;
  const int nb = (rem & 31) * 64;
  const int kb = (rem >> 5) * 64;
  const int col = nb + (tid & 63);
  const int k0 = kb + (tid >> 6) * 16;
  float v[16];
#pragma unroll
  for (int j = 0; j < 16; ++j)
    v[j] = src[(size_t)(k0 + j) * D + col];
  f16x8 h0, h1;
#pragma unroll
  for (int j = 0; j < 8; ++j) { h0[j] = (f16)v[j]; h1[j] = (f16)v[8 + j]; }
  f16* dst = Bb + (size_t)col * KT + koff + k0;
  *(f16x8*)dst = h0;
  *(f16x8*)(dst + 8) = h1;
}

__global__ __launch_bounds__(256) void k_prep(
    const float* __restrict__ srcAl, const float* __restrict__ srcAu,
    f16* __restrict__ Bb) {
  transpose_panel(srcAl, srcAu, Bb, blockIdx.x, threadIdx.x);
}

// ---- step GEMM + fused bias-epilogue + co-resident backfill transpose ------
// 4 waves, per-wave 128x64 C (ratio 0.375 ds_read/MFMA), BK=32 -> rows 64 B:
// fragment ds_read_b128 tiles contiguous 1 KiB => conflict-free, no swizzle.
__global__ __launch_bounds__(256, 2) void k_gemm(
    const f16* __restrict__ A,     // [2D][KT] state
    const f16* __restrict__ BT,    // [D][KT] current layer (transposed)
    f16* __restrict__ BTn,         // next layer's B buffer (backfill target)
    const float* __restrict__ nAl, const float* __restrict__ nAu,
    const float* __restrict__ w1, const float* __restrict__ w2,
    float* __restrict__ bdst,      // blbu (t<7) or outacc (t=7)
    f16* __restrict__ An) {        // [2D][KT] next state
  __shared__ __align__(16) f16 lds[3 * BUFSZ];   // 72 KiB tri-buffer

  if (blockIdx.x >= 256) {   // backfill: transpose next layer (co-resident)
    transpose_panel(nAl, nAu, BTn, blockIdx.x - 256, threadIdx.x);
    return;
  }

  // bijective XCD swizzle over the 16x16 tile grid
  const int flat = blockIdx.x;
  const int xcd = flat & 7, idx = flat >> 3;
  const int by = (xcd >> 1) * 4 + (idx >> 3);
  const int bx = (xcd & 1) * 8 + (idx & 7);
  const int m0 = by * BM;
  const int n0 = bx * BN;

  const int tid = threadIdx.x;
  const int wave = tid >> 6, lane = tid & 63;
  const int wm = (wave >> 1) * 128, wn = (wave & 1) * 64;
  const int lr = lane & 15, lq = lane >> 4;
  const int srow = lane >> 2;        // staging row within 16-row chunk
  const int scol = (lane & 3) * 8;   // staging f16 offset within 64-B row

  f32x4 acc[8][4];
#pragma unroll
  for (int m = 0; m < 8; ++m)
#pragma unroll
    for (int n = 0; n < 4; ++n)
      acc[m][n] = (f32x4){0.f, 0.f, 0.f, 0.f};

  // stage one K-tile: 6 gload16 per wave (4 A-chunks + 2 B-chunks of 16 rows)
  auto stage = [&](int kt, int buf) {
    f16* bA = lds + buf * BUFSZ;
    f16* bB = bA + BM * BK;
    const size_t gk = (size_t)kt * BK;
#pragma unroll
    for (int i = 0; i < 4; ++i) {
      const int r = i * 4 + wave;             // A chunks 0..15
      gload16(A + (size_t)(m0 + r * 16 + srow) * KT + gk + scol, bA + r * 512);
    }
#pragma unroll
    for (int i = 0; i < 2; ++i) {
      const int r = i * 4 + wave;             // B chunks 0..7
      gload16(BT + (size_t)(n0 + r * 16 + srow) * KT + gk + scol, bB + r * 512);
    }
  };

  stage(0, 0);
  stage(1, 1);
  asm volatile("s_waitcnt vmcnt(6)" ::: "memory");
  __builtin_amdgcn_sched_barrier(0);
  __builtin_amdgcn_s_barrier();
  __builtin_amdgcn_sched_barrier(0);

  for (int t = 0; t < NT; ++t) {
    const f16* bA = lds + (t % 3) * BUFSZ;
    const f16* bB = bA + BM * BK;
    if (t + 2 < NT) stage(t + 2, (t + 2) % 3);   // prefetch 2 tiles ahead
    f16x8 af[8], bf[4];
#pragma unroll
    for (int m = 0; m < 8; ++m)
      af[m] = *(const f16x8*)(bA + (wm + m * 16 + lr) * BK + lq * 8);
#pragma unroll
    for (int n = 0; n < 4; ++n)
      bf[n] = *(const f16x8*)(bB + (wn + n * 16 + lr) * BK + lq * 8);
    __builtin_amdgcn_s_setprio(1);
#pragma unroll
    for (int m = 0; m < 8; ++m)
#pragma unroll
      for (int n = 0; n < 4; ++n)
        acc[m][n] = __builtin_amdgcn_mfma_f32_16x16x32_f16(
            bf[n], af[m], acc[m][n], 0, 0, 0);
    __builtin_amdgcn_s_setprio(0);
    if (t + 2 < NT) {
      asm volatile("s_waitcnt vmcnt(6)" ::: "memory");
    } else if (t + 1 < NT) {
      asm volatile("s_waitcnt vmcnt(0)" ::: "memory");
    }
    __builtin_amdgcn_sched_barrier(0);
    __builtin_amdgcn_s_barrier();
    __builtin_amdgcn_sched_barrier(0);
  }

  // ---- epilogue: sign-split store + fused bias contribution ----
  const int low = (m0 < D) ? 1 : 0;
  f32x4 w1v[4], w2v[4];
#pragma unroll
  for (int n = 0; n < 4; ++n) {
    const int col = n0 + wn + n * 16 + lq * 4;
    w1v[n] = *(const f32x4*)(w1 + col);
    w2v[n] = *(const f32x4*)(w2 + col);
  }
  float rowsum[8] = {0.f, 0.f, 0.f, 0.f, 0.f, 0.f, 0.f, 0.f};
#pragma unroll
  for (int m = 0; m < 8; ++m) {
#pragma unroll
    for (int n = 0; n < 4; ++n) {
      const size_t row = (size_t)(m0 + wm + m * 16 + lr);
      const int col = n0 + wn + n * 16 + lq * 4;
      f16x4 p, q;
#pragma unroll
      for (int r = 0; r < 4; ++r) {
        float v = acc[m][n][r];
        float pf = fmaxf(v, 0.f), qf = fminf(v, 0.f);
        p[r] = (f16)pf;
        q[r] = (f16)qf;
        float wa = low ? w1v[n][r] : w2v[n][r];
        float wb = low ? w2v[n][r] : w1v[n][r];
        rowsum[m] += pf * wa + qf * wb;
      }
      f16* base = An + row * KT + col;
      if (low) { *(f16x4*)base = p; *(f16x4*)(base + D) = q; }
      else     { *(f16x4*)base = q; *(f16x4*)(base + D) = p; }
    }
  }
#pragma unroll
  for (int m = 0; m < 8; ++m) {
    float v = rowsum[m];
    v += __shfl_down(v, 32);
    v += __shfl_down(v, 16);
    if (lane < 16)
      atomicAdd(bdst + m0 + wm + m * 16 + lane, v);
  }
}

// ---- final: out[R] = outacc[R] + blbu[R] -----------------------------------
__global__ __launch_bounds__(256) void k_final(
    const float* __restrict__ outacc, const float* __restrict__ blbu,
    float* __restrict__ out) {
  const int R = blockIdx.x * 256 + threadIdx.x;
  out[R] = outacc[R] + blbu[R];
}

// ---- host ------------------------------------------------------------------
extern "C" void kernel_launch(void* const* d_in, const int* in_sizes, int n_in,
                              void* d_out, int out_size, void* d_ws, size_t ws_size,
                              hipStream_t stream) {
  (void)in_sizes; (void)n_in; (void)out_size;
  const float* A   = (const float*)d_in[0];
  const float* b   = (const float*)d_in[1];
  const float* hAl = (const float*)d_in[2];
  const float* hAu = (const float*)d_in[3];
  const float* hbl = (const float*)d_in[4];
  const float* hbu = (const float*)d_in[5];
  const float* lo  = (const float*)d_in[6];
  const float* up  = (const float*)d_in[7];
  float* out = (float*)d_out;

  const size_t AS = (size_t)2 * D * KT;     // Abig elems (f16)
  const size_t BS = (size_t)D * KT;         // Bb elems (f16)
  const size_t MS = (size_t)D * D;
  char* base = (char*)d_ws;
  f16* Ab0   = (f16*)base;
  f16* Ab1   = Ab0 + AS;
  f16* Bb0   = Ab1 + AS;
  float* blbu   = (float*)(Bb0 + BS);
  float* outacc = blbu + 2 * D;
  f16* Bb1   = (f16*)(outacc + 2 * D);
  const size_t need_fused = (size_t)((char*)(Bb1 + BS) - base);
  const bool fused = ws_size >= need_fused;

  k_init<<<dim3(D), 256, 0, stream>>>(
      A, b, hbl + (size_t)7 * D, hbu + (size_t)7 * D, Ab0, blbu, outacc);
  k_prep<<<dim3(2048), 256, 0, stream>>>(          // layer 7 -> Bb0
      hAl + (size_t)7 * MS, hAu + (size_t)7 * MS, Bb0);

  f16* cur = Ab0;
  f16* nxt = Ab1;
  for (int t = 0; t < L; ++t) {
    const int nlayer = 6 - t;   // layer for step t+1 (bias weights + transpose)
    const float* w1 = (t < 7) ? hbl + (size_t)nlayer * D : lo;
    const float* w2 = (t < 7) ? hbu + (size_t)nlayer * D : up;
    float* bd = (t < 7) ? blbu : outacc;
    f16* BT  = (fused && (t & 1)) ? Bb1 : Bb0;
    f16* BTn = fused ? ((t & 1) ? Bb0 : Bb1) : Bb0;
    const float* nl = (t < 7) ? hAl + (size_t)nlayer * MS : hAl;
    const float* nu = (t < 7) ? hAu + (size_t)nlayer * MS : hAu;
    if (!fused && t > 0)
      k_prep<<<dim3(2048), 256, 0, stream>>>(
          hAl + (size_t)(7 - t) * MS, hAu + (size_t)(7 - t) * MS, Bb0);
    const unsigned grid = (fused && t < 7) ? 2304u : 256u;
    k_gemm<<<dim3(grid), 256, 0, stream>>>(cur, BT, BTn, nl, nu, w1, w2, bd, nxt);
    f16* tmp = cur; cur = nxt; nxt = tmp;
  }
  k_final<<<dim3(2 * D / 256), 256, 0, stream>>>(outacc, blbu, out);
}

// Round 6
// 726.769 us; speedup vs baseline: 1.0523x; 1.0523x over previous
//
#include <hip/hip_runtime.h>
#include <cstdint>
#include <cstddef>

#define D 2048
#define L 8
#define KT 4096            // stacked K (pos|neg)
#define BM 256
#define BN 128
#define BK 32
#define NT (KT / BK)       // 128 K-tiles
#define BUFSZ ((BM + BN) * BK)   // 12288 f16 = 24 KiB per LDS buffer

typedef _Float16 f16;
typedef _Float16 f16x4 __attribute__((ext_vector_type(4)));
typedef _Float16 f16x8 __attribute__((ext_vector_type(8)));
typedef float f32x4 __attribute__((ext_vector_type(4)));

__device__ __forceinline__ void gload16(const void* g, void* l) {
  __builtin_amdgcn_global_load_lds(
      (const __attribute__((address_space(1))) void*)g,
      (__attribute__((address_space(3))) void*)l, 16, 0, 0);
}

// ---- init: A -> Abig = [[A+|A-];[A-|A+]], bias init + step-0 contribution --
__global__ __launch_bounds__(256) void k_init(
    const float* __restrict__ A, const float* __restrict__ b,
    const float* __restrict__ db1, const float* __restrict__ db2,  // layer 7
    f16* __restrict__ Ab, float* __restrict__ blbu, float* __restrict__ outacc) {
  const int m = blockIdx.x, tid = threadIdx.x;
  if (m < 2) {
    f32x4 z = {0.f, 0.f, 0.f, 0.f};
    *(f32x4*)(outacc + m * 2048 + tid * 8) = z;
    *(f32x4*)(outacc + m * 2048 + tid * 8 + 4) = z;
  }
  const int k = tid * 8;
  size_t i = (size_t)m * D + k;
  f32x4 a0 = *(const f32x4*)(A + i);
  f32x4 a1 = *(const f32x4*)(A + i + 4);
  f16x8 p, n;
  float cL = 0.f, cU = 0.f;
#pragma unroll
  for (int j = 0; j < 8; ++j) {
    float v = (j < 4) ? a0[j] : a1[j - 4];
    float pf = fmaxf(v, 0.f), nf = fminf(v, 0.f);
    p[j] = (f16)pf; n[j] = (f16)nf;
    float w1 = db1[k + j], w2 = db2[k + j];
    cL += pf * w1 + nf * w2;
    cU += pf * w2 + nf * w1;
  }
  size_t lo = (size_t)m * KT + k;
  size_t hi = (size_t)(D + m) * KT + k;
  *(f16x8*)(Ab + lo) = p;      *(f16x8*)(Ab + lo + D) = n;
  *(f16x8*)(Ab + hi) = n;      *(f16x8*)(Ab + hi + D) = p;

  __shared__ float redL[4], redU[4];
#pragma unroll
  for (int off = 32; off > 0; off >>= 1) {
    cL += __shfl_down(cL, off);
    cU += __shfl_down(cU, off);
  }
  const int wave = tid >> 6, lane = tid & 63;
  if (lane == 0) { redL[wave] = cL; redU[wave] = cU; }
  __syncthreads();
  if (tid == 0) {
    float bL = b[m] + redL[0] + redL[1] + redL[2] + redL[3];
    float bU = b[m] + redU[0] + redU[1] + redU[2] + redU[3];
    blbu[m] = bL; blbu[D + m] = bU;
  }
}

// ---- LDS-free transpose panel: Bb[n][koff+k] = (f16)src[k][n] --------------
// blk in [0,2048): 1024 blocks per matrix; block covers 64 cols x 64 k
__device__ __forceinline__ void transpose_panel(
    const float* __restrict__ srcAl, const float* __restrict__ srcAu,
    f16* __restrict__ Bb, int blk, int tid) {
  const int z = blk >> 10;
  const int rem = blk & 1023;
  const float* src = z ? srcAu : srcAl;
  const int koff = z ? D : 0;
  const int nb = (rem & 31) * 64;
  const int kb = (rem >> 5) * 64;
  const int col = nb + (tid & 63);
  const int k0 = kb + (tid >> 6) * 16;
  float v[16];
#pragma unroll
  for (int j = 0; j < 16; ++j)
    v[j] = src[(size_t)(k0 + j) * D + col];
  f16x8 h0, h1;
#pragma unroll
  for (int j = 0; j < 8; ++j) { h0[j] = (f16)v[j]; h1[j] = (f16)v[8 + j]; }
  f16* dst = Bb + (size_t)col * KT + koff + k0;
  *(f16x8*)dst = h0;
  *(f16x8*)(dst + 8) = h1;
}

__global__ __launch_bounds__(256) void k_prep(
    const float* __restrict__ srcAl, const float* __restrict__ srcAu,
    f16* __restrict__ Bb) {
  transpose_panel(srcAl, srcAu, Bb, blockIdx.x, threadIdx.x);
}

// ---- step GEMM + fused bias-epilogue + co-resident backfill transpose ------
// 4 waves, per-wave 128x64 C. BK=32 rows are 64 B: logical chunk c of row r
// is stored at physical chunk c^((r>>1)&3) -> every quarter-wave b128 phase
// hits each bank pair exactly twice (2-way = free). gload_lds writes linear
// (phys chunk = lane), so the GLOBAL source is pre-swizzled per rule 21.
__global__ __launch_bounds__(256, 2) void k_gemm(
    const f16* __restrict__ A,     // [2D][KT] state
    const f16* __restrict__ BT,    // [D][KT] current layer (transposed)
    f16* __restrict__ BTn,         // next layer's B buffer (backfill target)
    const float* __restrict__ nAl, const float* __restrict__ nAu,
    const float* __restrict__ w1, const float* __restrict__ w2,
    float* __restrict__ bdst,      // blbu (t<7) or outacc (t=7)
    f16* __restrict__ An) {        // [2D][KT] next state
  __shared__ __align__(16) f16 lds[3 * BUFSZ];   // 72 KiB tri-buffer

  if (blockIdx.x >= 256) {   // backfill: transpose next layer (co-resident)
    transpose_panel(nAl, nAu, BTn, blockIdx.x - 256, threadIdx.x);
    return;
  }

  // bijective XCD swizzle over the 16x16 tile grid
  const int flat = blockIdx.x;
  const int xcd = flat & 7, idx = flat >> 3;
  const int by = (xcd >> 1) * 4 + (idx >> 3);
  const int bx = (xcd & 1) * 8 + (idx & 7);
  const int m0 = by * BM;
  const int n0 = bx * BN;

  const int tid = threadIdx.x;
  const int wave = tid >> 6, lane = tid & 63;
  const int wm = (wave >> 1) * 128, wn = (wave & 1) * 64;
  const int lr = lane & 15, lq = lane >> 4;
  const int srow = lane >> 2;                        // staging row in 16-row chunk
  const int scol = ((lane & 3) ^ ((lane >> 3) & 3)) * 8;  // pre-swizzled src chunk
  const int rchunk = (lq ^ ((lr >> 1) & 3)) * 8;     // swizzled read chunk (f16)

  f32x4 acc[8][4];
#pragma unroll
  for (int m = 0; m < 8; ++m)
#pragma unroll
    for (int n = 0; n < 4; ++n)
      acc[m][n] = (f32x4){0.f, 0.f, 0.f, 0.f};

  // stage one K-tile: 6 gload16 per wave (4 A-chunks + 2 B-chunks of 16 rows)
  auto stage = [&](int kt, int buf) {
    f16* bA = lds + buf * BUFSZ;
    f16* bB = bA + BM * BK;
    const size_t gk = (size_t)kt * BK;
#pragma unroll
    for (int i = 0; i < 4; ++i) {
      const int r = i * 4 + wave;             // A chunks 0..15
      gload16(A + (size_t)(m0 + r * 16 + srow) * KT + gk + scol, bA + r * 512);
    }
#pragma unroll
    for (int i = 0; i < 2; ++i) {
      const int r = i * 4 + wave;             // B chunks 0..7
      gload16(BT + (size_t)(n0 + r * 16 + srow) * KT + gk + scol, bB + r * 512);
    }
  };

  stage(0, 0);
  stage(1, 1);
  asm volatile("s_waitcnt vmcnt(6)" ::: "memory");
  __builtin_amdgcn_sched_barrier(0);
  __builtin_amdgcn_s_barrier();
  __builtin_amdgcn_sched_barrier(0);

  for (int t = 0; t < NT; ++t) {
    const f16* bA = lds + (t % 3) * BUFSZ;
    const f16* bB = bA + BM * BK;
    if (t + 2 < NT) stage(t + 2, (t + 2) % 3);   // prefetch 2 tiles ahead
    f16x8 af[8], bf[4];
#pragma unroll
    for (int m = 0; m < 8; ++m)
      af[m] = *(const f16x8*)(bA + (wm + m * 16 + lr) * BK + rchunk);
#pragma unroll
    for (int n = 0; n < 4; ++n)
      bf[n] = *(const f16x8*)(bB + (wn + n * 16 + lr) * BK + rchunk);
    __builtin_amdgcn_s_setprio(1);
#pragma unroll
    for (int m = 0; m < 8; ++m)
#pragma unroll
      for (int n = 0; n < 4; ++n)
        acc[m][n] = __builtin_amdgcn_mfma_f32_16x16x32_f16(
            bf[n], af[m], acc[m][n], 0, 0, 0);
    __builtin_amdgcn_s_setprio(0);
    if (t + 2 < NT) {
      asm volatile("s_waitcnt vmcnt(6)" ::: "memory");
    } else if (t + 1 < NT) {
      asm volatile("s_waitcnt vmcnt(0)" ::: "memory");
    }
    __builtin_amdgcn_sched_barrier(0);
    __builtin_amdgcn_s_barrier();
    __builtin_amdgcn_sched_barrier(0);
  }

  // ---- epilogue: sign-split store + fused bias contribution ----
  const int low = (m0 < D) ? 1 : 0;
  f32x4 w1v[4], w2v[4];
#pragma unroll
  for (int n = 0; n < 4; ++n) {
    const int col = n0 + wn + n * 16 + lq * 4;
    w1v[n] = *(const f32x4*)(w1 + col);
    w2v[n] = *(const f32x4*)(w2 + col);
  }
  float rowsum[8] = {0.f, 0.f, 0.f, 0.f, 0.f, 0.f, 0.f, 0.f};
#pragma unroll
  for (int m = 0; m < 8; ++m) {
#pragma unroll
    for (int n = 0; n < 4; ++n) {
      const size_t row = (size_t)(m0 + wm + m * 16 + lr);
      const int col = n0 + wn + n * 16 + lq * 4;
      f16x4 p, q;
#pragma unroll
      for (int r = 0; r < 4; ++r) {
        float v = acc[m][n][r];
        float pf = fmaxf(v, 0.f), qf = fminf(v, 0.f);
        p[r] = (f16)pf;
        q[r] = (f16)qf;
        float wa = low ? w1v[n][r] : w2v[n][r];
        float wb = low ? w2v[n][r] : w1v[n][r];
        rowsum[m] += pf * wa + qf * wb;
      }
      f16* base = An + row * KT + col;
      if (low) { *(f16x4*)base = p; *(f16x4*)(base + D) = q; }
      else     { *(f16x4*)base = q; *(f16x4*)(base + D) = p; }
    }
  }
#pragma unroll
  for (int m = 0; m < 8; ++m) {
    float v = rowsum[m];
    v += __shfl_down(v, 32);
    v += __shfl_down(v, 16);
    if (lane < 16)
      atomicAdd(bdst + m0 + wm + m * 16 + lane, v);
  }
}

// ---- final: out[R] = outacc[R] + blbu[R] -----------------------------------
__global__ __launch_bounds__(256) void k_final(
    const float* __restrict__ outacc, const float* __restrict__ blbu,
    float* __restrict__ out) {
  const int R = blockIdx.x * 256 + threadIdx.x;
  out[R] = outacc[R] + blbu[R];
}

// ---- host ------------------------------------------------------------------
extern "C" void kernel_launch(void* const* d_in, const int* in_sizes, int n_in,
                              void* d_out, int out_size, void* d_ws, size_t ws_size,
                              hipStream_t stream) {
  (void)in_sizes; (void)n_in; (void)out_size;
  const float* A   = (const float*)d_in[0];
  const float* b   = (const float*)d_in[1];
  const float* hAl = (const float*)d_in[2];
  const float* hAu = (const float*)d_in[3];
  const float* hbl = (const float*)d_in[4];
  const float* hbu = (const float*)d_in[5];
  const float* lo  = (const float*)d_in[6];
  const float* up  = (const float*)d_in[7];
  float* out = (float*)d_out;

  const size_t AS = (size_t)2 * D * KT;     // Abig elems (f16)
  const size_t BS = (size_t)D * KT;         // Bb elems (f16)
  const size_t MS = (size_t)D * D;
  char* base = (char*)d_ws;
  f16* Ab0   = (f16*)base;
  f16* Ab1   = Ab0 + AS;
  f16* Bb0   = Ab1 + AS;
  float* blbu   = (float*)(Bb0 + BS);
  float* outacc = blbu + 2 * D;
  f16* Bb1   = (f16*)(outacc + 2 * D);
  const size_t need_fused = (size_t)((char*)(Bb1 + BS) - base);
  const bool fused = ws_size >= need_fused;

  k_init<<<dim3(D), 256, 0, stream>>>(
      A, b, hbl + (size_t)7 * D, hbu + (size_t)7 * D, Ab0, blbu, outacc);
  k_prep<<<dim3(2048), 256, 0, stream>>>(          // layer 7 -> Bb0
      hAl + (size_t)7 * MS, hAu + (size_t)7 * MS, Bb0);

  f16* cur = Ab0;
  f16* nxt = Ab1;
  for (int t = 0; t < L; ++t) {
    const int nlayer = 6 - t;   // layer for step t+1 (bias weights + transpose)
    const float* w1 = (t < 7) ? hbl + (size_t)nlayer * D : lo;
    const float* w2 = (t < 7) ? hbu + (size_t)nlayer * D : up;
    float* bd = (t < 7) ? blbu : outacc;
    f16* BT  = (fused && (t & 1)) ? Bb1 : Bb0;
    f16* BTn = fused ? ((t & 1) ? Bb0 : Bb1) : Bb0;
    const float* nl = (t < 7) ? hAl + (size_t)nlayer * MS : hAl;
    const float* nu = (t < 7) ? hAu + (size_t)nlayer * MS : hAu;
    if (!fused && t > 0)
      k_prep<<<dim3(2048), 256, 0, stream>>>(
          hAl + (size_t)(7 - t) * MS, hAu + (size_t)(7 - t) * MS, Bb0);
    const unsigned grid = (fused && t < 7) ? 2304u : 256u;
    k_gemm<<<dim3(grid), 256, 0, stream>>>(cur, BT, BTn, nl, nu, w1, w2, bd, nxt);
    f16* tmp = cur; cur = nxt; nxt = tmp;
  }
  k_final<<<dim3(2 * D / 256), 256, 0, stream>>>(outacc, blbu, out);
}